// Round 2
// baseline (153.511 us; speedup 1.0000x reference)
//
#include <hip/hip_runtime.h>
#include <hip/hip_bf16.h>

// Problem: output = embeddings[unseen_index] (200 floats). Only edges with
// edge_dst == unseen_index contribute (~E/N = 8 of 400000 expected).
// Phase 1: filter edges (int4-vectorized scan of edge_dst, 1.6 MB).
// Phase 2: per (i-chunk, edge) block, compute partial message directly from
//          basis (no W_r materialization), atomicAdd into ws accumulator;
//          last block to finish normalizes and writes d_out.

#define DE 200
#define IN_DIM 400
#define ICHUNK 50          // IN_DIM / 8
#define NCHUNK 8
#define MAXJ 64

// ws layout (ints): [0]=count, [1]=done, [64..264)=acc floats, [1024..)=list
#define WS_ACC_OFF   64
#define WS_LIST_OFF  1024

__global__ void filter_k(const int4* __restrict__ edge_dst4,
                         const int* __restrict__ edge_dst,
                         const int* __restrict__ unseen,
                         int n4, int n_edges,
                         int* __restrict__ ws_count,
                         int* __restrict__ ws_list, int max_list) {
    const int u = unseen[0];
    int idx = blockIdx.x * blockDim.x + threadIdx.x;
    for (; idx < n4; idx += gridDim.x * blockDim.x) {
        const int4 v = edge_dst4[idx];
        const int e = idx * 4;
        if (v.x == u) { int p = atomicAdd(ws_count, 1); if (p < max_list) ws_list[p] = e;     }
        if (v.y == u) { int p = atomicAdd(ws_count, 1); if (p < max_list) ws_list[p] = e + 1; }
        if (v.z == u) { int p = atomicAdd(ws_count, 1); if (p < max_list) ws_list[p] = e + 2; }
        if (v.w == u) { int p = atomicAdd(ws_count, 1); if (p < max_list) ws_list[p] = e + 3; }
    }
    // tail (n_edges % 4), handled by first few threads of block 0
    if (blockIdx.x == 0 && threadIdx.x < (n_edges & 3)) {
        const int e = n4 * 4 + threadIdx.x;
        if (edge_dst[e] == u) { int p = atomicAdd(ws_count, 1); if (p < max_list) ws_list[p] = e; }
    }
}

__global__ void compute_k(const float* __restrict__ Eemb,
                          const float* __restrict__ Remb,
                          const float* __restrict__ basis,
                          const float* __restrict__ att,
                          const int* __restrict__ node_id,
                          const int* __restrict__ edge_src,
                          const int* __restrict__ edge_type,
                          const int* __restrict__ rel_index,
                          int* __restrict__ ws,          // count/done/acc
                          const int* __restrict__ ws_list,
                          float* __restrict__ out, int max_list) {
    int* ws_count = ws;
    int* ws_done  = ws + 1;
    float* acc    = (float*)ws + WS_ACC_OFF;

    int cnt = ws_count[0];
    int cl = cnt > max_list ? max_list : cnt;
    const int base = blockIdx.x * ICHUNK;   // i-chunk base
    const int t = threadIdx.x;
    __shared__ float s_xj[ICHUNK];
    __shared__ int s_last;
    float m = 0.f;
    bool any = false;

    for (int j = blockIdx.y; j < cl; j += gridDim.y) {
        const int e   = ws_list[j];
        const int src = edge_src[e];
        const int typ = edge_type[e];
        const int ri  = rel_index[e];
        __syncthreads();               // protect s_xj from prior-iter readers
        if (t < ICHUNK) {
            const int i = base + t;
            s_xj[t] = (i < DE) ? Eemb[(size_t)node_id[src] * DE + i]
                               : Remb[(size_t)ri * DE + (i - DE)];
        }
        __syncthreads();
        if (t < DE) {
            const float a0 = att[typ * 4 + 0];
            const float a1 = att[typ * 4 + 1];
            const float a2 = att[typ * 4 + 2];
            const float a3 = att[typ * 4 + 3];
            float h0 = 0.f, h1 = 0.f, h2 = 0.f, h3 = 0.f;
            // basis[b][i][o] at (b*IN_DIM + i)*DE + o ; b-stride = 80000
            #pragma unroll 5
            for (int ii = 0; ii < ICHUNK; ++ii) {
                const float xv = s_xj[ii];
                const int off = (base + ii) * DE + t;
                h0 += xv * basis[off];
                h1 += xv * basis[off + 80000];
                h2 += xv * basis[off + 160000];
                h3 += xv * basis[off + 240000];
            }
            m += a0 * h0 + a1 * h1 + a2 * h2 + a3 * h3;
            any = true;
        }
    }
    if (any) atomicAdd(&acc[t], m);

    // last-block-done finalization (replaces separate finalize kernel)
    __threadfence();
    if (t == 0) {
        const int total = gridDim.x * gridDim.y;
        s_last = (atomicAdd(ws_done, 1) == total - 1) ? 1 : 0;
    }
    __syncthreads();
    if (s_last && t < DE) {
        int c = cnt;                       // written before this kernel launched
        if (c < 1) c = 1;
        const float v = atomicAdd(&acc[t], 0.0f);  // device-coherent read
        out[t] = v / (float)c;
    }
}

extern "C" void kernel_launch(void* const* d_in, const int* in_sizes, int n_in,
                              void* d_out, int out_size, void* d_ws, size_t ws_size,
                              hipStream_t stream) {
    const float* Eemb  = (const float*)d_in[0];
    const float* Remb  = (const float*)d_in[1];
    const float* basis = (const float*)d_in[2];
    const float* att   = (const float*)d_in[3];
    const int* node_id  = (const int*)d_in[4];
    const int* edge_src = (const int*)d_in[5];
    const int* edge_dst = (const int*)d_in[6];
    const int* edge_typ = (const int*)d_in[7];
    const int* rel_idx  = (const int*)d_in[8];
    const int* unseen   = (const int*)d_in[9];
    float* out = (float*)d_out;

    const int n_edges = in_sizes[6];
    const int n4 = n_edges / 4;

    int* ws      = (int*)d_ws;
    int* ws_list = (int*)d_ws + WS_LIST_OFF;
    long avail = (long)(ws_size / 4) - WS_LIST_OFF;
    int max_list = avail > 8192 ? 8192 : (avail > 0 ? (int)avail : 0);

    // zero count/done/acc (d_ws is poisoned to 0xAA before every launch)
    hipMemsetAsync(d_ws, 0, 2048, stream);

    const int fblocks = (n4 + 255) / 256;
    filter_k<<<fblocks, 256, 0, stream>>>((const int4*)edge_dst, edge_dst,
                                          unseen, n4, n_edges, ws, ws_list,
                                          max_list);

    dim3 cgrid(NCHUNK, MAXJ);
    compute_k<<<cgrid, 256, 0, stream>>>(Eemb, Remb, basis, att, node_id,
                                         edge_src, edge_typ, rel_idx,
                                         ws, ws_list, out, max_list);
}

// Round 3
// 130.407 us; speedup vs baseline: 1.1772x; 1.1772x over previous
//
#include <hip/hip_runtime.h>
#include <hip/hip_bf16.h>

// Problem: output = embeddings[unseen_index] (200 floats). Only edges with
// edge_dst == unseen_index contribute (~E/N = 8 of 400000 expected).
// Phase 1: filter edges (int4-vectorized scan of edge_dst, 1.6 MB).
// Phase 2: per (i-chunk, edge-slot) block, compute partial message directly
//          from basis (no W_r materialization), atomicAdd into ws acc.
// Phase 3: tiny finalize kernel divides by count.
// Measured round 1/2: total dur is dominated by harness ws-poison fill
// (320 MB, ~48 us @ ~84% HBM peak) + input restores; these kernels are ~10 us.

#define DE 200
#define IN_DIM 400
#define ICHUNK 50          // IN_DIM / 8
#define NCHUNK 8
#define MAXJ 32

// ws layout (ints): [0]=count, [64..264)=acc floats, [1024..)=match list
#define WS_ACC_OFF   64
#define WS_LIST_OFF  1024

__global__ void filter_k(const int4* __restrict__ edge_dst4,
                         const int* __restrict__ edge_dst,
                         const int* __restrict__ unseen,
                         int n4, int n_edges,
                         int* __restrict__ ws_count,
                         int* __restrict__ ws_list, int max_list) {
    const int u = unseen[0];
    int idx = blockIdx.x * blockDim.x + threadIdx.x;
    for (; idx < n4; idx += gridDim.x * blockDim.x) {
        const int4 v = edge_dst4[idx];
        const int e = idx * 4;
        if (v.x == u) { int p = atomicAdd(ws_count, 1); if (p < max_list) ws_list[p] = e;     }
        if (v.y == u) { int p = atomicAdd(ws_count, 1); if (p < max_list) ws_list[p] = e + 1; }
        if (v.z == u) { int p = atomicAdd(ws_count, 1); if (p < max_list) ws_list[p] = e + 2; }
        if (v.w == u) { int p = atomicAdd(ws_count, 1); if (p < max_list) ws_list[p] = e + 3; }
    }
    if (blockIdx.x == 0 && threadIdx.x < (n_edges & 3)) {
        const int e = n4 * 4 + threadIdx.x;
        if (edge_dst[e] == u) { int p = atomicAdd(ws_count, 1); if (p < max_list) ws_list[p] = e; }
    }
}

__global__ void compute_k(const float* __restrict__ Eemb,
                          const float* __restrict__ Remb,
                          const float* __restrict__ basis,
                          const float* __restrict__ att,
                          const int* __restrict__ node_id,
                          const int* __restrict__ edge_src,
                          const int* __restrict__ edge_type,
                          const int* __restrict__ rel_index,
                          const int* __restrict__ ws_count,
                          const int* __restrict__ ws_list,
                          float* __restrict__ acc, int max_list) {
    int cnt = ws_count[0];
    if (cnt > max_list) cnt = max_list;
    const int base = blockIdx.x * ICHUNK;   // i-chunk base
    const int t = threadIdx.x;
    __shared__ float s_xj[ICHUNK];
    float m = 0.f;
    bool any = false;

    for (int j = blockIdx.y; j < cnt; j += gridDim.y) {
        const int e   = ws_list[j];
        const int src = edge_src[e];
        const int typ = edge_type[e];
        const int ri  = rel_index[e];
        __syncthreads();               // protect s_xj from prior-iter readers
        if (t < ICHUNK) {
            const int i = base + t;
            s_xj[t] = (i < DE) ? Eemb[(size_t)node_id[src] * DE + i]
                               : Remb[(size_t)ri * DE + (i - DE)];
        }
        __syncthreads();
        if (t < DE) {
            const float a0 = att[typ * 4 + 0];
            const float a1 = att[typ * 4 + 1];
            const float a2 = att[typ * 4 + 2];
            const float a3 = att[typ * 4 + 3];
            float h0 = 0.f, h1 = 0.f, h2 = 0.f, h3 = 0.f;
            // basis[b][i][o] at (b*IN_DIM + i)*DE + o ; b-stride = 80000
            #pragma unroll 5
            for (int ii = 0; ii < ICHUNK; ++ii) {
                const float xv = s_xj[ii];
                const int off = (base + ii) * DE + t;
                h0 += xv * basis[off];
                h1 += xv * basis[off + 80000];
                h2 += xv * basis[off + 160000];
                h3 += xv * basis[off + 240000];
            }
            m += a0 * h0 + a1 * h1 + a2 * h2 + a3 * h3;
            any = true;
        }
    }
    if (any) atomicAdd(&acc[t], m);
}

__global__ void finalize_k(const int* __restrict__ ws_count,
                           const float* __restrict__ acc,
                           float* __restrict__ out) {
    const int t = threadIdx.x;
    if (t < DE) {
        int c = ws_count[0];
        if (c < 1) c = 1;
        out[t] = acc[t] / (float)c;
    }
}

extern "C" void kernel_launch(void* const* d_in, const int* in_sizes, int n_in,
                              void* d_out, int out_size, void* d_ws, size_t ws_size,
                              hipStream_t stream) {
    const float* Eemb  = (const float*)d_in[0];
    const float* Remb  = (const float*)d_in[1];
    const float* basis = (const float*)d_in[2];
    const float* att   = (const float*)d_in[3];
    const int* node_id  = (const int*)d_in[4];
    const int* edge_src = (const int*)d_in[5];
    const int* edge_dst = (const int*)d_in[6];
    const int* edge_typ = (const int*)d_in[7];
    const int* rel_idx  = (const int*)d_in[8];
    const int* unseen   = (const int*)d_in[9];
    float* out = (float*)d_out;

    const int n_edges = in_sizes[6];
    const int n4 = n_edges / 4;

    int* ws_count = (int*)d_ws;
    float* acc    = (float*)d_ws + WS_ACC_OFF;
    int* ws_list  = (int*)d_ws + WS_LIST_OFF;
    long avail = (long)(ws_size / 4) - WS_LIST_OFF;
    int max_list = avail > 8192 ? 8192 : (avail > 0 ? (int)avail : 0);

    // zero count + accumulator (d_ws is poisoned to 0xAA before every launch)
    hipMemsetAsync(d_ws, 0, 2048, stream);

    const int fblocks = (n4 + 255) / 256;
    filter_k<<<fblocks, 256, 0, stream>>>((const int4*)edge_dst, edge_dst,
                                          unseen, n4, n_edges, ws_count,
                                          ws_list, max_list);

    dim3 cgrid(NCHUNK, MAXJ);
    compute_k<<<cgrid, 256, 0, stream>>>(Eemb, Remb, basis, att, node_id,
                                         edge_src, edge_typ, rel_idx,
                                         ws_count, ws_list, acc, max_list);

    finalize_k<<<1, 256, 0, stream>>>(ws_count, acc, out);
}